// Round 6
// baseline (243.248 us; speedup 1.0000x reference)
//
#include <hip/hip_runtime.h>
#include <hip/hip_bf16.h>

namespace {

constexpr int kT = 4096;
constexpr int kHid = 1024;
constexpr int kNH = 8;
constexpr int kHS = 128;
constexpr int kNSlots = 8192;
constexpr float kEps = 1e-6f;
constexpr float kScale = 0.08838834764831845f;           // 128^-0.5
constexpr float kQScale = 0.12753102242f;                 // kScale * log2(e)
constexpr float kNeg = -1e30f;

typedef __attribute__((ext_vector_type(8))) short bf16x8;
typedef __attribute__((ext_vector_type(4))) float f32x4;
typedef __attribute__((ext_vector_type(16))) float f32x16;

__device__ __forceinline__ short f2bf(float x) {
  unsigned u = __builtin_bit_cast(unsigned, x);
  unsigned r = (u + 0x7FFFu + ((u >> 16) & 1u)) >> 16;
  return (short)r;
}

__device__ __forceinline__ bf16x8 pack_bf8(float4 a, float4 b) {
  bf16x8 r;
  r[0] = f2bf(a.x); r[1] = f2bf(a.y); r[2] = f2bf(a.z); r[3] = f2bf(a.w);
  r[4] = f2bf(b.x); r[5] = f2bf(b.y); r[6] = f2bf(b.z); r[7] = f2bf(b.w);
  return r;
}

__device__ __forceinline__ unsigned cvt_pk_bf16(float lo, float hi_) {
  unsigned r;
  asm("v_cvt_pk_bf16_f32 %0, %1, %2" : "=v"(r) : "v"(lo), "v"(hi_));
  return r;
}

__device__ __forceinline__ bf16x8 frag_from(unsigned w0, unsigned w1,
                                            unsigned w2, unsigned w3) {
  union { unsigned u[4]; bf16x8 v; } t;
  t.u[0] = w0; t.u[1] = w1; t.u[2] = w2; t.u[3] = w3;
  return t.v;
}

// 16B-slot XOR swizzle for [row][32 bf16] LDS tiles (64B rows) in the GEMMs.
__device__ __forceinline__ int swz(int r) { return ((r >> 1) ^ (r >> 3)) & 3; }

__device__ __forceinline__ void stage16(short* tile, int r, int k0,
                                        float4 a, float4 b, float4 c, float4 d) {
  const int sw = swz(r);
  const int s0 = k0 >> 3;  // 0 or 2
  *(bf16x8*)&tile[r * 32 + (((s0 + 0) ^ sw) << 3)] = pack_bf8(a, b);
  *(bf16x8*)&tile[r * 32 + (((s0 + 1) ^ sw) << 3)] = pack_bf8(c, d);
}

// Attention K tile: [64 key rows][128 d shorts] = 256B rows, 16-slot swizzle.
__device__ __forceinline__ short* kptr(short* base, int r, int c) {
  return (short*)((char*)base + ((r * 256 + c * 2) ^ ((r & 15) << 4)));
}
__device__ __forceinline__ const short* kptr(const short* base, int r, int c) {
  return (const short*)((const char*)base + ((r * 256 + c * 2) ^ ((r & 15) << 4)));
}
// Attention V tile, packed: V^T[d][k] at row=d>>1, col=(d&1)*64+k -> 256B rows.
__device__ __forceinline__ short* vptr2(short* base, int d, int k) {
  const int row = d >> 1;
  return (short*)((char*)base +
                  ((row * 256 + ((d & 1) * 64 + k) * 2) ^ ((row & 15) << 4)));
}
__device__ __forceinline__ const short* vptr2(const short* base, int d, int k) {
  const int row = d >> 1;
  return (const short*)((const char*)base +
                  ((row * 256 + ((d & 1) * 64 + k) * 2) ^ ((row & 15) << 4)));
}

// ---------------------------------------------------------------------------
// QKV GEMM (bf16 MFMA). Epilogue: l2norm + RoPE; Q pre-scaled by
// kScale*log2(e) (attention softmax runs in exp2 domain).
// ---------------------------------------------------------------------------
__global__ __launch_bounds__(256)
void qkv_gemm_kernel(const float* __restrict__ H, const float* __restrict__ W,
                     const float* __restrict__ cosb, const float* __restrict__ sinb,
                     const int* __restrict__ slots,
                     short* __restrict__ Qb, short* __restrict__ Kb,
                     short* __restrict__ Vb,
                     float* __restrict__ ock, float* __restrict__ ocv) {
  __shared__ short As[128 * 32];
  __shared__ short Bs[128 * 32];
  const int row0 = blockIdx.x * 128;
  const int bc = blockIdx.y;            // 0..7 q, 8..15 k, 16..23 v
  const int col0 = bc * 128;
  const int tid = threadIdx.x;
  const int lane = tid & 63, w = tid >> 6;
  const int lm = lane & 15, lg = lane >> 4;
  const int r_st = tid >> 1, k_st = (tid & 1) * 16;

  f32x4 acc[2][8];
#pragma unroll
  for (int rt = 0; rt < 2; ++rt)
#pragma unroll
    for (int ct = 0; ct < 8; ++ct) acc[rt][ct] = (f32x4){0.f, 0.f, 0.f, 0.f};

  const float* ap = H + (size_t)(row0 + r_st) * kHid + k_st;
  const float* bp = W + (size_t)(col0 + r_st) * kHid + k_st;
  const int arow0 = w * 32 + lm, arow1 = w * 32 + 16 + lm;

  for (int k0 = 0; k0 < kHid; k0 += 32) {
    const float4 a0 = *(const float4*)(ap + k0);
    const float4 a1 = *(const float4*)(ap + k0 + 4);
    const float4 a2 = *(const float4*)(ap + k0 + 8);
    const float4 a3 = *(const float4*)(ap + k0 + 12);
    const float4 b0 = *(const float4*)(bp + k0);
    const float4 b1 = *(const float4*)(bp + k0 + 4);
    const float4 b2 = *(const float4*)(bp + k0 + 8);
    const float4 b3 = *(const float4*)(bp + k0 + 12);
    __syncthreads();
    stage16(As, r_st, k_st, a0, a1, a2, a3);
    stage16(Bs, r_st, k_st, b0, b1, b2, b3);
    __syncthreads();
    const bf16x8 af0 = *(const bf16x8*)&As[arow0 * 32 + ((lg ^ swz(arow0)) << 3)];
    const bf16x8 af1 = *(const bf16x8*)&As[arow1 * 32 + ((lg ^ swz(arow1)) << 3)];
#pragma unroll
    for (int ct = 0; ct < 8; ++ct) {
      const int brow = ct * 16 + lm;
      const bf16x8 bb = *(const bf16x8*)&Bs[brow * 32 + ((lg ^ swz(brow)) << 3)];
      acc[0][ct] = __builtin_amdgcn_mfma_f32_16x16x32_bf16(af0, bb, acc[0][ct], 0, 0, 0);
      acc[1][ct] = __builtin_amdgcn_mfma_f32_16x16x32_bf16(af1, bb, acc[1][ct], 0, 0, 0);
    }
  }

  const bool isv = (bc >= 16);
  const int h = bc & 7;
#pragma unroll
  for (int rt = 0; rt < 2; ++rt) {
#pragma unroll
    for (int r = 0; r < 4; ++r) {
      const int t = row0 + w * 32 + rt * 16 + lg * 4 + r;
      const int slot = slots[t];
      if (!isv) {
        float ss = 0.f;
#pragma unroll
        for (int ct = 0; ct < 8; ++ct) ss = fmaf(acc[rt][ct][r], acc[rt][ct][r], ss);
        ss += __shfl_xor(ss, 1);
        ss += __shfl_xor(ss, 2);
        ss += __shfl_xor(ss, 4);
        ss += __shfl_xor(ss, 8);
        const float rs = rsqrtf(ss * (1.f / 128.f) + kEps);
#pragma unroll
        for (int ct = 0; ct < 8; ++ct) {
          const int col = ct * 16 + lm;
          const float x = acc[rt][ct][r] * rs;
          const float partner = __shfl_xor(x, 1);
          const float c = cosb[t * 64 + (col >> 1)];
          const float s = sinb[t * 64 + (col >> 1)];
          const float val = (lm & 1) ? fmaf(partner, s, x * c) : fmaf(-partner, s, x * c);
          if (bc < 8) {
            Qb[(size_t)t * kHid + h * kHS + col] = f2bf(val * kQScale);
          } else {
            ock[(size_t)slot * kHid + h * kHS + col] = val;
            Kb[(size_t)t * kHid + h * kHS + col] = f2bf(val);
          }
        }
      } else {
#pragma unroll
        for (int ct = 0; ct < 8; ++ct) {
          const int col = ct * 16 + lm;
          const float val = acc[rt][ct][r];
          ocv[(size_t)slot * kHid + h * kHS + col] = val;
          Vb[(size_t)t * kHid + h * kHS + col] = f2bf(val);
        }
      }
    }
  }
}

// ---------------------------------------------------------------------------
// Flash attention v6: dispatch-independent load balance. One block = one
// (head, pair a): processes q-tiles {63-a, a} SEQUENTIALLY -> every block
// does exactly 65 K-tile steps regardless of CU assignment. Grid 256
// (1 block/CU). Producer/consumer wave split + dbuf LDS as v5.
// ---------------------------------------------------------------------------
__global__ __launch_bounds__(256, 2)
void attn_kernel(const short* __restrict__ Qb, const short* __restrict__ Kb,
                 const short* __restrict__ Vb, short* __restrict__ abuf) {
  __shared__ short Ks[2][64 * 128];   // [buf][key][d], swizzled, 256B rows
  __shared__ short Vp[2][64 * 128];   // [buf][d>>1][(d&1)*64+k], swizzled
  __shared__ float bcast[2][32];      // per-consumer-wave alpha / 1/l

  const int flat = blockIdx.x;
  const int h = flat & 7;             // XCD round-robin -> head locality
  const int a = flat >> 3;            // 0..31: pair {63-a, a}
  const int tid = threadIdx.x;
  const int w = tid >> 6;
  const int lane = tid & 63;
  const int lq = lane & 31, hi = lane >> 5;
  const bool consumer = (w < 2);
  const int wc = w & 1;

  if (!consumer) {
    // -------- producer: stage K (row-major) + V (packed-T), dbuf --------
    const int ptid = wc * 64 + lane;               // 0..127
    const int krow = ptid >> 1, kcol = (ptid & 1) * 64;
    const int vk = (ptid & 31) * 2, vd0 = (ptid >> 5) * 4;

    auto stage = [&](int j0, short* KsB, short* VpB) {
      const short* kp = Kb + (size_t)(j0 + krow) * kHid + h * kHS + kcol;
      bf16x8 kr[8];
#pragma unroll
      for (int u = 0; u < 8; ++u) kr[u] = *(const bf16x8*)(kp + u * 8);
      ushort4 va[8], vb4[8];
#pragma unroll
      for (int p = 0; p < 8; ++p) {
        const int d0 = vd0 + p * 16;
        va[p] = *(const ushort4*)&Vb[(size_t)(j0 + vk) * kHid + h * kHS + d0];
        vb4[p] = *(const ushort4*)&Vb[(size_t)(j0 + vk + 1) * kHid + h * kHS + d0];
      }
#pragma unroll
      for (int u = 0; u < 8; ++u) *(bf16x8*)kptr(KsB, krow, kcol + u * 8) = kr[u];
#pragma unroll
      for (int p = 0; p < 8; ++p) {
        const int d0 = vd0 + p * 16;
        const unsigned lo[4] = {va[p].x, va[p].y, va[p].z, va[p].w};
        const unsigned hh[4] = {vb4[p].x, vb4[p].y, vb4[p].z, vb4[p].w};
#pragma unroll
        for (int ii = 0; ii < 4; ++ii)
          *(unsigned*)vptr2(VpB, d0 + ii, vk) = lo[ii] | (hh[ii] << 16);
      }
    };

#pragma unroll 1
    for (int phase = 0; phase < 2; ++phase) {
      const int qt = phase ? a : (63 - a);
      const int nsteps = qt + 1;
      stage(0, Ks[0], Vp[0]);
      __syncthreads();
#pragma unroll 1
      for (int s = 0; s < nsteps; ++s) {
        if (s + 1 < nsteps) stage((s + 1) * 64, Ks[(s + 1) & 1], Vp[(s + 1) & 1]);
        __syncthreads();
      }
    }
    return;
  }

  // -------------------------- consumer ---------------------------------
#pragma unroll 1
  for (int phase = 0; phase < 2; ++phase) {
    const int qt = phase ? a : (63 - a);
    const int q0 = qt * 64;
    const int nsteps = qt + 1;
    const int qrow = q0 + wc * 32 + lq;            // this lane's q row

    // Q fragments (B-operand): lane gives Q[q=lq][dc*16+hi*8 .. +7].
    bf16x8 qf[8];
    {
      const short* qp = Qb + (size_t)qrow * kHid + h * kHS + hi * 8;
#pragma unroll
      for (int dc = 0; dc < 8; ++dc) qf[dc] = *(const bf16x8*)(qp + dc * 16);
    }

    float m = kNeg, l = 0.f;
    f32x16 O[4];
#pragma unroll
    for (int dt = 0; dt < 4; ++dt)
#pragma unroll
      for (int r = 0; r < 16; ++r) O[dt][r] = 0.f;

    __syncthreads();  // buf0 staged

#pragma unroll 1
    for (int s = 0; s < nsteps; ++s) {
      const int j0 = s * 64;
      const short* KsB = Ks[s & 1];
      const short* VpB = Vp[s & 1];

      // ---- S^T = K · Q (exp2-domain scores).
      f32x16 st[2];
#pragma unroll
      for (int kb = 0; kb < 2; ++kb)
#pragma unroll
        for (int r = 0; r < 16; ++r) st[kb][r] = 0.f;

      __builtin_amdgcn_s_setprio(1);
#pragma unroll
      for (int dc = 0; dc < 8; ++dc) {
#pragma unroll
        for (int kb = 0; kb < 2; ++kb) {
          const bf16x8 a2 = *(const bf16x8*)kptr(KsB, kb * 32 + lq, dc * 16 + hi * 8);
          st[kb] = __builtin_amdgcn_mfma_f32_32x32x16_bf16(a2, qf[dc], st[kb], 0, 0, 0);
        }
      }
      __builtin_amdgcn_s_setprio(0);

      // ---- causal mask (diagonal tile only).
      if (j0 == q0) {
#pragma unroll
        for (int kb = 0; kb < 2; ++kb)
#pragma unroll
          for (int r = 0; r < 16; ++r) {
            const int ka = j0 + kb * 32 + (r & 3) + 8 * (r >> 2) + 4 * hi;
            if (ka > qrow) st[kb][r] = kNeg;
          }
      }

      // ---- online softmax with defer-max (T13).
      float tt[16];
#pragma unroll
      for (int r = 0; r < 16; ++r) tt[r] = fmaxf(st[0][r], st[1][r]);
#pragma unroll
      for (int d = 8; d >= 1; d >>= 1)
#pragma unroll
        for (int r = 0; r < d; ++r) tt[r] = fmaxf(tt[r], tt[r + d]);
      const float pmax = fmaxf(tt[0], __shfl_xor(tt[0], 32));

      if (!__all(pmax - m <= 8.f)) {
        const float mnew = fmaxf(m, pmax);
        const float alpha = exp2f(m - mnew);
        m = mnew;
        l *= alpha;
        if (!hi) bcast[wc][lq] = alpha;
        float4 av[4];
#pragma unroll
        for (int g = 0; g < 4; ++g) av[g] = *(const float4*)&bcast[wc][8 * g + 4 * hi];
#pragma unroll
        for (int dt = 0; dt < 4; ++dt)
#pragma unroll
          for (int r = 0; r < 16; ++r) O[dt][r] *= av[r >> 2][r & 3];
      }

      float ts[16];
#pragma unroll
      for (int kb = 0; kb < 2; ++kb)
#pragma unroll
        for (int r = 0; r < 16; ++r) st[kb][r] = exp2f(st[kb][r] - m);
#pragma unroll
      for (int r = 0; r < 16; ++r) ts[r] = st[0][r] + st[1][r];
#pragma unroll
      for (int d = 8; d >= 1; d >>= 1)
#pragma unroll
        for (int r = 0; r < d; ++r) ts[r] += ts[r + d];
      l += ts[0] + __shfl_xor(ts[0], 32);

      // ---- P -> bf16 A-fragments via cvt_pk + lane^32 exchange (T12).
      bf16x8 pf[4];
#pragma unroll
      for (int kb = 0; kb < 2; ++kb) {
        unsigned wq[8];
#pragma unroll
        for (int u = 0; u < 8; ++u)
          wq[u] = cvt_pk_bf16(st[kb][2 * u], st[kb][2 * u + 1]);
        {
          const unsigned z0 = hi ? wq[0] : wq[2];
          const unsigned z1 = hi ? wq[1] : wq[3];
          const unsigned s0 = __shfl_xor(z0, 32);
          const unsigned s1 = __shfl_xor(z1, 32);
          pf[2 * kb] = frag_from(hi ? s0 : wq[0], hi ? s1 : wq[1],
                                 hi ? wq[2] : s0, hi ? wq[3] : s1);
        }
        {
          const unsigned z0 = hi ? wq[4] : wq[6];
          const unsigned z1 = hi ? wq[5] : wq[7];
          const unsigned s0 = __shfl_xor(z0, 32);
          const unsigned s1 = __shfl_xor(z1, 32);
          pf[2 * kb + 1] = frag_from(hi ? s0 : wq[4], hi ? s1 : wq[5],
                                     hi ? wq[6] : s0, hi ? wq[7] : s1);
        }
      }

      // ---- O += P · V.
      __builtin_amdgcn_s_setprio(1);
#pragma unroll
      for (int kc = 0; kc < 4; ++kc) {
#pragma unroll
        for (int dt = 0; dt < 4; ++dt) {
          const bf16x8 b = *(const bf16x8*)vptr2(VpB, dt * 32 + lq, kc * 16 + hi * 8);
          O[dt] = __builtin_amdgcn_mfma_f32_32x32x16_bf16(pf[kc], b, O[dt], 0, 0, 0);
        }
      }
      __builtin_amdgcn_s_setprio(0);

      __syncthreads();  // next buf staged; this buf free
    }

    // ---- write out: O col = d = dt*32+lq, row = (r&3)+8*(r>>2)+4*hi.
    if (!hi) bcast[wc][lq] = 1.f / l;
    float4 iv[4];
#pragma unroll
    for (int g = 0; g < 4; ++g) iv[g] = *(const float4*)&bcast[wc][8 * g + 4 * hi];
#pragma unroll
    for (int dt = 0; dt < 4; ++dt)
#pragma unroll
      for (int r = 0; r < 16; ++r) {
        const int mrow = (r & 3) + 8 * (r >> 2) + 4 * hi;
        const int t = q0 + wc * 32 + mrow;
        abuf[(size_t)t * kHid + h * kHS + dt * 32 + lq] =
            f2bf(O[dt][r] * iv[r >> 2][r & 3]);
      }
  }
}

// ---------------------------------------------------------------------------
// Output GEMM (bf16 MFMA): unchanged.
// ---------------------------------------------------------------------------
__global__ __launch_bounds__(256)
void out_gemm_kernel(const short* __restrict__ A, const float* __restrict__ W,
                     float* __restrict__ C) {
  __shared__ short As[128 * 32];
  __shared__ short Bs[128 * 32];
  const int row0 = blockIdx.x * 128;
  const int col0 = blockIdx.y * 128;
  const int tid = threadIdx.x;
  const int lane = tid & 63, w = tid >> 6;
  const int lm = lane & 15, lg = lane >> 4;
  const int r_st = tid >> 1, k_st = (tid & 1) * 16;

  f32x4 acc[2][8];
#pragma unroll
  for (int rt = 0; rt < 2; ++rt)
#pragma unroll
    for (int ct = 0; ct < 8; ++ct) acc[rt][ct] = (f32x4){0.f, 0.f, 0.f, 0.f};

  const short* ap = A + (size_t)(row0 + r_st) * kHid + k_st;
  const float* bp = W + (size_t)(col0 + r_st) * kHid + k_st;
  const int arow0 = w * 32 + lm, arow1 = w * 32 + 16 + lm;

  for (int k0 = 0; k0 < kHid; k0 += 32) {
    const bf16x8 a0 = *(const bf16x8*)(ap + k0);
    const bf16x8 a1 = *(const bf16x8*)(ap + k0 + 8);
    const float4 b0 = *(const float4*)(bp + k0);
    const float4 b1 = *(const float4*)(bp + k0 + 4);
    const float4 b2 = *(const float4*)(bp + k0 + 8);
    const float4 b3 = *(const float4*)(bp + k0 + 12);
    __syncthreads();
    {
      const int sw = swz(r_st);
      const int s0 = k_st >> 3;
      *(bf16x8*)&As[r_st * 32 + (((s0 + 0) ^ sw) << 3)] = a0;
      *(bf16x8*)&As[r_st * 32 + (((s0 + 1) ^ sw) << 3)] = a1;
    }
    stage16(Bs, r_st, k_st, b0, b1, b2, b3);
    __syncthreads();
    const bf16x8 af0 = *(const bf16x8*)&As[arow0 * 32 + ((lg ^ swz(arow0)) << 3)];
    const bf16x8 af1 = *(const bf16x8*)&As[arow1 * 32 + ((lg ^ swz(arow1)) << 3)];
#pragma unroll
    for (int ct = 0; ct < 8; ++ct) {
      const int brow = ct * 16 + lm;
      const bf16x8 bb = *(const bf16x8*)&Bs[brow * 32 + ((lg ^ swz(brow)) << 3)];
      acc[0][ct] = __builtin_amdgcn_mfma_f32_16x16x32_bf16(af0, bb, acc[0][ct], 0, 0, 0);
      acc[1][ct] = __builtin_amdgcn_mfma_f32_16x16x32_bf16(af1, bb, acc[1][ct], 0, 0, 0);
    }
  }

#pragma unroll
  for (int rt = 0; rt < 2; ++rt)
#pragma unroll
    for (int r = 0; r < 4; ++r) {
      const int row = row0 + w * 32 + rt * 16 + lg * 4 + r;
#pragma unroll
      for (int ct = 0; ct < 8; ++ct)
        C[(size_t)row * kHid + col0 + ct * 16 + lm] = acc[rt][ct][r];
    }
}

}  // namespace

extern "C" void kernel_launch(void* const* d_in, const int* in_sizes, int n_in,
                              void* d_out, int out_size, void* d_ws, size_t ws_size,
                              hipStream_t stream) {
  (void)in_sizes; (void)n_in; (void)out_size; (void)ws_size;
  const float* H = (const float*)d_in[0];
  const float* cosb = (const float*)d_in[1];
  const float* sinb = (const float*)d_in[2];
  const float* Wqkv = (const float*)d_in[3];
  const float* Wo = (const float*)d_in[4];
  const int* slots = (const int*)d_in[5];
  const float* ck = (const float*)d_in[6];
  const float* cv = (const float*)d_in[7];

  float* out = (float*)d_out;
  float* ock = out + (size_t)kT * kHid;             // new_cache_k (f32)
  float* ocv = ock + (size_t)kNSlots * kNH * kHS;   // new_cache_v (f32)

  short* Qb = (short*)out;       // borrow out region (dead until out_gemm)
  short* Kb = Qb + (size_t)kT * kHid;
  short* Vb = (short*)d_ws;
  short* abuf = Vb + (size_t)kT * kHid;

  const size_t cache_bytes = (size_t)kNSlots * kNH * kHS * sizeof(float);
  hipMemcpyAsync(ock, ck, cache_bytes, hipMemcpyDeviceToDevice, stream);
  hipMemcpyAsync(ocv, cv, cache_bytes, hipMemcpyDeviceToDevice, stream);

  qkv_gemm_kernel<<<dim3(kT / 128, 24), 256, 0, stream>>>(
      H, Wqkv, cosb, sinb, slots, Qb, Kb, Vb, ock, ocv);
  attn_kernel<<<256, 256, 0, stream>>>(Qb, Kb, Vb, abuf);
  out_gemm_kernel<<<dim3(kT / 128, kHid / 128), 256, 0, stream>>>(abuf, Wo, out);
}

// Round 7
// 242.675 us; speedup vs baseline: 1.0024x; 1.0024x over previous
//
#include <hip/hip_runtime.h>
#include <hip/hip_bf16.h>

namespace {

constexpr int kT = 4096;
constexpr int kHid = 1024;
constexpr int kNH = 8;
constexpr int kHS = 128;
constexpr int kNSlots = 8192;
constexpr float kEps = 1e-6f;
constexpr float kScale = 0.08838834764831845f;           // 128^-0.5
constexpr float kQScale = 0.12753102242f;                 // kScale * log2(e)
constexpr float kNeg = -1e30f;

typedef __attribute__((ext_vector_type(8))) short bf16x8;
typedef __attribute__((ext_vector_type(4))) float f32x4;
typedef __attribute__((ext_vector_type(16))) float f32x16;

__device__ __forceinline__ short f2bf(float x) {
  unsigned u = __builtin_bit_cast(unsigned, x);
  unsigned r = (u + 0x7FFFu + ((u >> 16) & 1u)) >> 16;
  return (short)r;
}

__device__ __forceinline__ bf16x8 pack_bf8(float4 a, float4 b) {
  bf16x8 r;
  r[0] = f2bf(a.x); r[1] = f2bf(a.y); r[2] = f2bf(a.z); r[3] = f2bf(a.w);
  r[4] = f2bf(b.x); r[5] = f2bf(b.y); r[6] = f2bf(b.z); r[7] = f2bf(b.w);
  return r;
}

__device__ __forceinline__ unsigned cvt_pk_bf16(float lo, float hi_) {
  unsigned r;
  asm("v_cvt_pk_bf16_f32 %0, %1, %2" : "=v"(r) : "v"(lo), "v"(hi_));
  return r;
}

__device__ __forceinline__ bf16x8 frag_from(unsigned w0, unsigned w1,
                                            unsigned w2, unsigned w3) {
  union { unsigned u[4]; bf16x8 v; } t;
  t.u[0] = w0; t.u[1] = w1; t.u[2] = w2; t.u[3] = w3;
  return t.v;
}

// 16B-slot XOR swizzle for [row][32 bf16] LDS tiles (64B rows) in the GEMMs.
__device__ __forceinline__ int swz(int r) { return ((r >> 1) ^ (r >> 3)) & 3; }

__device__ __forceinline__ void stage16(short* tile, int r, int k0,
                                        float4 a, float4 b, float4 c, float4 d) {
  const int sw = swz(r);
  const int s0 = k0 >> 3;  // 0 or 2
  *(bf16x8*)&tile[r * 32 + (((s0 + 0) ^ sw) << 3)] = pack_bf8(a, b);
  *(bf16x8*)&tile[r * 32 + (((s0 + 1) ^ sw) << 3)] = pack_bf8(c, d);
}

// Attention K tile: [64 key rows][128 d shorts] = 256B rows, 16-slot swizzle.
__device__ __forceinline__ short* kptr(short* base, int r, int c) {
  return (short*)((char*)base + ((r * 256 + c * 2) ^ ((r & 15) << 4)));
}
__device__ __forceinline__ const short* kptr(const short* base, int r, int c) {
  return (const short*)((const char*)base + ((r * 256 + c * 2) ^ ((r & 15) << 4)));
}
// Attention V tile, packed: V^T[d][k] at row=d>>1, col=(d&1)*64+k -> 256B rows.
__device__ __forceinline__ short* vptr2(short* base, int d, int k) {
  const int row = d >> 1;
  return (short*)((char*)base +
                  ((row * 256 + ((d & 1) * 64 + k) * 2) ^ ((row & 15) << 4)));
}
__device__ __forceinline__ const short* vptr2(const short* base, int d, int k) {
  const int row = d >> 1;
  return (const short*)((const char*)base +
                  ((row * 256 + ((d & 1) * 64 + k) * 2) ^ ((row & 15) << 4)));
}

// ---------------------------------------------------------------------------
// QKV GEMM (bf16 MFMA). Epilogue: l2norm + RoPE; Q pre-scaled by
// kScale*log2(e) (attention softmax runs in exp2 domain). Unchanged.
// ---------------------------------------------------------------------------
__global__ __launch_bounds__(256)
void qkv_gemm_kernel(const float* __restrict__ H, const float* __restrict__ W,
                     const float* __restrict__ cosb, const float* __restrict__ sinb,
                     const int* __restrict__ slots,
                     short* __restrict__ Qb, short* __restrict__ Kb,
                     short* __restrict__ Vb,
                     float* __restrict__ ock, float* __restrict__ ocv) {
  __shared__ short As[128 * 32];
  __shared__ short Bs[128 * 32];
  const int row0 = blockIdx.x * 128;
  const int bc = blockIdx.y;            // 0..7 q, 8..15 k, 16..23 v
  const int col0 = bc * 128;
  const int tid = threadIdx.x;
  const int lane = tid & 63, w = tid >> 6;
  const int lm = lane & 15, lg = lane >> 4;
  const int r_st = tid >> 1, k_st = (tid & 1) * 16;

  f32x4 acc[2][8];
#pragma unroll
  for (int rt = 0; rt < 2; ++rt)
#pragma unroll
    for (int ct = 0; ct < 8; ++ct) acc[rt][ct] = (f32x4){0.f, 0.f, 0.f, 0.f};

  const float* ap = H + (size_t)(row0 + r_st) * kHid + k_st;
  const float* bp = W + (size_t)(col0 + r_st) * kHid + k_st;
  const int arow0 = w * 32 + lm, arow1 = w * 32 + 16 + lm;

  for (int k0 = 0; k0 < kHid; k0 += 32) {
    const float4 a0 = *(const float4*)(ap + k0);
    const float4 a1 = *(const float4*)(ap + k0 + 4);
    const float4 a2 = *(const float4*)(ap + k0 + 8);
    const float4 a3 = *(const float4*)(ap + k0 + 12);
    const float4 b0 = *(const float4*)(bp + k0);
    const float4 b1 = *(const float4*)(bp + k0 + 4);
    const float4 b2 = *(const float4*)(bp + k0 + 8);
    const float4 b3 = *(const float4*)(bp + k0 + 12);
    __syncthreads();
    stage16(As, r_st, k_st, a0, a1, a2, a3);
    stage16(Bs, r_st, k_st, b0, b1, b2, b3);
    __syncthreads();
    const bf16x8 af0 = *(const bf16x8*)&As[arow0 * 32 + ((lg ^ swz(arow0)) << 3)];
    const bf16x8 af1 = *(const bf16x8*)&As[arow1 * 32 + ((lg ^ swz(arow1)) << 3)];
#pragma unroll
    for (int ct = 0; ct < 8; ++ct) {
      const int brow = ct * 16 + lm;
      const bf16x8 bb = *(const bf16x8*)&Bs[brow * 32 + ((lg ^ swz(brow)) << 3)];
      acc[0][ct] = __builtin_amdgcn_mfma_f32_16x16x32_bf16(af0, bb, acc[0][ct], 0, 0, 0);
      acc[1][ct] = __builtin_amdgcn_mfma_f32_16x16x32_bf16(af1, bb, acc[1][ct], 0, 0, 0);
    }
  }

  const bool isv = (bc >= 16);
  const int h = bc & 7;
#pragma unroll
  for (int rt = 0; rt < 2; ++rt) {
#pragma unroll
    for (int r = 0; r < 4; ++r) {
      const int t = row0 + w * 32 + rt * 16 + lg * 4 + r;
      const int slot = slots[t];
      if (!isv) {
        float ss = 0.f;
#pragma unroll
        for (int ct = 0; ct < 8; ++ct) ss = fmaf(acc[rt][ct][r], acc[rt][ct][r], ss);
        ss += __shfl_xor(ss, 1);
        ss += __shfl_xor(ss, 2);
        ss += __shfl_xor(ss, 4);
        ss += __shfl_xor(ss, 8);
        const float rs = rsqrtf(ss * (1.f / 128.f) + kEps);
#pragma unroll
        for (int ct = 0; ct < 8; ++ct) {
          const int col = ct * 16 + lm;
          const float x = acc[rt][ct][r] * rs;
          const float partner = __shfl_xor(x, 1);
          const float c = cosb[t * 64 + (col >> 1)];
          const float s = sinb[t * 64 + (col >> 1)];
          const float val = (lm & 1) ? fmaf(partner, s, x * c) : fmaf(-partner, s, x * c);
          if (bc < 8) {
            Qb[(size_t)t * kHid + h * kHS + col] = f2bf(val * kQScale);
          } else {
            ock[(size_t)slot * kHid + h * kHS + col] = val;
            Kb[(size_t)t * kHid + h * kHS + col] = f2bf(val);
          }
        }
      } else {
#pragma unroll
        for (int ct = 0; ct < 8; ++ct) {
          const int col = ct * 16 + lm;
          const float val = acc[rt][ct][r];
          ocv[(size_t)slot * kHid + h * kHS + col] = val;
          Vb[(size_t)t * kHid + h * kHS + col] = f2bf(val);
        }
      }
    }
  }
}

// ---------------------------------------------------------------------------
// Flash attention v7: 8 waves/block (4 consumers + 4 producers), split-K
// across consumer groups (group 0 = even K-tiles, group 1 = odd), independent
// online-softmax states merged once per phase via LDS. 4-deep LDS ring.
// Grid 256, block = (head, pair a) processing q-tiles {63-a, a} sequentially
// -> every block runs exactly 33 rounds. 2 waves/SIMD (1C+1P).
// ---------------------------------------------------------------------------
__global__ __launch_bounds__(512, 2)
void attn_kernel(const short* __restrict__ Qb, const short* __restrict__ Kb,
                 const short* __restrict__ Vb, short* __restrict__ abuf) {
  __shared__ short KV[4][2][64 * 128];  // [buf][0=K,1=Vpacked][...], swizzled
  __shared__ float bcast[4][32];        // per consumer wave: alpha / f0
  __shared__ float mml[2][64];          // group1 m,l ; reused for f1

  const int flat = blockIdx.x;
  const int h = flat & 7;               // XCD round-robin -> head locality
  const int a = flat >> 3;              // 0..31: pair {63-a, a}
  const int tid = threadIdx.x;
  const int w = tid >> 6;
  const int lane = tid & 63;
  const int lq = lane & 31, hi = lane >> 5;
  const bool isC = (w < 4);
  const int g = (w >> 1) & 1;           // consumer K-parity group
  const int wc = w & 1;                 // q-row half (0: rows 0-31, 1: 32-63)

  // Producer lane geometry.
  const int pw = (w - 4) & 3;
  const int pg = (pw >> 1) & 1;         // producer pair: stages tiles of parity
  const int ptid = (pw & 1) * 64 + lane;
  const int krow = ptid >> 1, kcol = (ptid & 1) * 64;
  const int vk = (ptid & 31) * 2, vd0 = (ptid >> 5) * 4;

  auto stageT = [&](int j0, int buf) {
    short* KsB = &KV[buf][0][0];
    short* VpB = &KV[buf][1][0];
    const short* kp = Kb + (size_t)(j0 + krow) * kHid + h * kHS + kcol;
    bf16x8 kr[8];
#pragma unroll
    for (int u = 0; u < 8; ++u) kr[u] = *(const bf16x8*)(kp + u * 8);
    ushort4 va[8], vb4[8];
#pragma unroll
    for (int p = 0; p < 8; ++p) {
      const int d0 = vd0 + p * 16;
      va[p] = *(const ushort4*)&Vb[(size_t)(j0 + vk) * kHid + h * kHS + d0];
      vb4[p] = *(const ushort4*)&Vb[(size_t)(j0 + vk + 1) * kHid + h * kHS + d0];
    }
#pragma unroll
    for (int u = 0; u < 8; ++u) *(bf16x8*)kptr(KsB, krow, kcol + u * 8) = kr[u];
#pragma unroll
    for (int p = 0; p < 8; ++p) {
      const int d0 = vd0 + p * 16;
      const unsigned lo[4] = {va[p].x, va[p].y, va[p].z, va[p].w};
      const unsigned hh[4] = {vb4[p].x, vb4[p].y, vb4[p].z, vb4[p].w};
#pragma unroll
      for (int ii = 0; ii < 4; ++ii)
        *(unsigned*)vptr2(VpB, d0 + ii, vk) = lo[ii] | (hh[ii] << 16);
    }
  };

#pragma unroll 1
  for (int phase = 0; phase < 2; ++phase) {
    const int qt = phase ? a : (63 - a);
    const int q0 = qt * 64;
    const int N = qt + 1;                 // K-tiles
    const int R = (N + 1) >> 1;           // rounds
    const int boff = phase * 2;           // ring offset per phase

    const int qrow = q0 + wc * 32 + lq;

    bf16x8 qf[8];
    float m = kNeg, l = 0.f;
    f32x16 O[4];
#pragma unroll
    for (int dt = 0; dt < 4; ++dt)
#pragma unroll
      for (int r = 0; r < 16; ++r) O[dt][r] = 0.f;

    if (isC) {
      const short* qp = Qb + (size_t)qrow * kHid + h * kHS + hi * 8;
#pragma unroll
      for (int dc = 0; dc < 8; ++dc) qf[dc] = *(const bf16x8*)(qp + dc * 16);
    } else {
      if (pg == 0) stageT(0, (0 + boff) & 3);
      else if (1 < N) stageT(64, (1 + boff) & 3);
    }
    __syncthreads();

#pragma unroll 1
    for (int k = 0; k < R; ++k) {
      if (isC) {
        const int t = 2 * k + g;
        if (t < N) {
          const int j0 = t * 64;
          const int buf = (t + boff) & 3;
          const short* KsB = &KV[buf][0][0];
          const short* VpB = &KV[buf][1][0];

          // ---- S^T = K · Q (exp2-domain scores).
          f32x16 st[2];
#pragma unroll
          for (int kb = 0; kb < 2; ++kb)
#pragma unroll
            for (int r = 0; r < 16; ++r) st[kb][r] = 0.f;

          __builtin_amdgcn_s_setprio(1);
#pragma unroll
          for (int dc = 0; dc < 8; ++dc) {
#pragma unroll
            for (int kb = 0; kb < 2; ++kb) {
              const bf16x8 a2 = *(const bf16x8*)kptr(KsB, kb * 32 + lq, dc * 16 + hi * 8);
              st[kb] = __builtin_amdgcn_mfma_f32_32x32x16_bf16(a2, qf[dc], st[kb], 0, 0, 0);
            }
          }
          __builtin_amdgcn_s_setprio(0);

          // ---- causal mask (diagonal tile only).
          if (j0 == q0) {
#pragma unroll
            for (int kb = 0; kb < 2; ++kb)
#pragma unroll
              for (int r = 0; r < 16; ++r) {
                const int ka = j0 + kb * 32 + (r & 3) + 8 * (r >> 2) + 4 * hi;
                if (ka > qrow) st[kb][r] = kNeg;
              }
          }

          // ---- online softmax with defer-max (T13).
          float tt[16];
#pragma unroll
          for (int r = 0; r < 16; ++r) tt[r] = fmaxf(st[0][r], st[1][r]);
#pragma unroll
          for (int d = 8; d >= 1; d >>= 1)
#pragma unroll
            for (int r = 0; r < d; ++r) tt[r] = fmaxf(tt[r], tt[r + d]);
          const float pmax = fmaxf(tt[0], __shfl_xor(tt[0], 32));

          if (!__all(pmax - m <= 8.f)) {
            const float mnew = fmaxf(m, pmax);
            const float alpha = exp2f(m - mnew);
            m = mnew;
            l *= alpha;
            if (!hi) bcast[w][lq] = alpha;
            float4 av[4];
#pragma unroll
            for (int g4 = 0; g4 < 4; ++g4)
              av[g4] = *(const float4*)&bcast[w][8 * g4 + 4 * hi];
#pragma unroll
            for (int dt = 0; dt < 4; ++dt)
#pragma unroll
              for (int r = 0; r < 16; ++r) O[dt][r] *= av[r >> 2][r & 3];
          }

          float ts[16];
#pragma unroll
          for (int kb = 0; kb < 2; ++kb)
#pragma unroll
            for (int r = 0; r < 16; ++r) st[kb][r] = exp2f(st[kb][r] - m);
#pragma unroll
          for (int r = 0; r < 16; ++r) ts[r] = st[0][r] + st[1][r];
#pragma unroll
          for (int d = 8; d >= 1; d >>= 1)
#pragma unroll
            for (int r = 0; r < d; ++r) ts[r] += ts[r + d];
          l += ts[0] + __shfl_xor(ts[0], 32);

          // ---- P -> bf16 A-fragments via cvt_pk + lane^32 exchange (T12).
          bf16x8 pf[4];
#pragma unroll
          for (int kb = 0; kb < 2; ++kb) {
            unsigned wq[8];
#pragma unroll
            for (int u = 0; u < 8; ++u)
              wq[u] = cvt_pk_bf16(st[kb][2 * u], st[kb][2 * u + 1]);
            {
              const unsigned z0 = hi ? wq[0] : wq[2];
              const unsigned z1 = hi ? wq[1] : wq[3];
              const unsigned s0 = __shfl_xor(z0, 32);
              const unsigned s1 = __shfl_xor(z1, 32);
              pf[2 * kb] = frag_from(hi ? s0 : wq[0], hi ? s1 : wq[1],
                                     hi ? wq[2] : s0, hi ? wq[3] : s1);
            }
            {
              const unsigned z0 = hi ? wq[4] : wq[6];
              const unsigned z1 = hi ? wq[5] : wq[7];
              const unsigned s0 = __shfl_xor(z0, 32);
              const unsigned s1 = __shfl_xor(z1, 32);
              pf[2 * kb + 1] = frag_from(hi ? s0 : wq[4], hi ? s1 : wq[5],
                                         hi ? wq[6] : s0, hi ? wq[7] : s1);
            }
          }

          // ---- O += P · V.
          __builtin_amdgcn_s_setprio(1);
#pragma unroll
          for (int kc = 0; kc < 4; ++kc) {
#pragma unroll
            for (int dt = 0; dt < 4; ++dt) {
              const bf16x8 b = *(const bf16x8*)vptr2(VpB, dt * 32 + lq, kc * 16 + hi * 8);
              O[dt] = __builtin_amdgcn_mfma_f32_32x32x16_bf16(pf[kc], b, O[dt], 0, 0, 0);
            }
          }
          __builtin_amdgcn_s_setprio(0);
        }
      } else {
        const int t2 = 2 * k + 2 + pg;
        if (t2 < N) stageT(t2 * 64, (t2 + boff) & 3);
      }
      __syncthreads();
    }

    // -------- merge group1 state into group0, write output --------
    float* mO = (float*)&KV[0][wc][0];  // 4096 floats per row-half wave
    if (isC && g == 1) {
      if (!hi) { mml[0][wc * 32 + lq] = m; mml[1][wc * 32 + lq] = l; }
#pragma unroll
      for (int dt = 0; dt < 4; ++dt)
#pragma unroll
        for (int r = 0; r < 16; ++r) mO[lane * 64 + dt * 16 + r] = O[dt][r];
    }
    __syncthreads();
    if (isC && g == 0) {
      const float m1 = mml[0][wc * 32 + lq];
      const float l1 = mml[1][wc * 32 + lq];
      const float ms = fmaxf(m, m1);
      const float a0 = exp2f(m - ms);
      const float a1 = exp2f(m1 - ms);
      const float linv = 1.f / (l * a0 + l1 * a1);
      // Per-q factors; broadcast to O-row layout via LDS.
      if (!hi) {
        bcast[w][lq] = a0 * linv;              // f0
        mml[0][wc * 32 + lq] = a1 * linv;      // f1 (mml[0] reads done above)
      }
      float4 f0v[4], f1v[4];
#pragma unroll
      for (int g4 = 0; g4 < 4; ++g4) {
        f0v[g4] = *(const float4*)&bcast[w][8 * g4 + 4 * hi];
        f1v[g4] = *(const float4*)&mml[0][wc * 32 + 8 * g4 + 4 * hi];
      }
#pragma unroll
      for (int dt = 0; dt < 4; ++dt)
#pragma unroll
        for (int r = 0; r < 16; ++r) {
          const int mrow = (r & 3) + 8 * (r >> 2) + 4 * hi;
          const int t = q0 + wc * 32 + mrow;
          const float o1 = mO[lane * 64 + dt * 16 + r];
          abuf[(size_t)t * kHid + h * kHS + dt * 32 + lq] =
              f2bf(O[dt][r] * f0v[r >> 2][r & 3] + o1 * f1v[r >> 2][r & 3]);
        }
    }
    __syncthreads();
  }
}

// ---------------------------------------------------------------------------
// Output GEMM (bf16 MFMA): unchanged.
// ---------------------------------------------------------------------------
__global__ __launch_bounds__(256)
void out_gemm_kernel(const short* __restrict__ A, const float* __restrict__ W,
                     float* __restrict__ C) {
  __shared__ short As[128 * 32];
  __shared__ short Bs[128 * 32];
  const int row0 = blockIdx.x * 128;
  const int col0 = blockIdx.y * 128;
  const int tid = threadIdx.x;
  const int lane = tid & 63, w = tid >> 6;
  const int lm = lane & 15, lg = lane >> 4;
  const int r_st = tid >> 1, k_st = (tid & 1) * 16;

  f32x4 acc[2][8];
#pragma unroll
  for (int rt = 0; rt < 2; ++rt)
#pragma unroll
    for (int ct = 0; ct < 8; ++ct) acc[rt][ct] = (f32x4){0.f, 0.f, 0.f, 0.f};

  const short* ap = A + (size_t)(row0 + r_st) * kHid + k_st;
  const float* bp = W + (size_t)(col0 + r_st) * kHid + k_st;
  const int arow0 = w * 32 + lm, arow1 = w * 32 + 16 + lm;

  for (int k0 = 0; k0 < kHid; k0 += 32) {
    const bf16x8 a0 = *(const bf16x8*)(ap + k0);
    const bf16x8 a1 = *(const bf16x8*)(ap + k0 + 8);
    const float4 b0 = *(const float4*)(bp + k0);
    const float4 b1 = *(const float4*)(bp + k0 + 4);
    const float4 b2 = *(const float4*)(bp + k0 + 8);
    const float4 b3 = *(const float4*)(bp + k0 + 12);
    __syncthreads();
    {
      const int sw = swz(r_st);
      const int s0 = k_st >> 3;
      *(bf16x8*)&As[r_st * 32 + (((s0 + 0) ^ sw) << 3)] = a0;
      *(bf16x8*)&As[r_st * 32 + (((s0 + 1) ^ sw) << 3)] = a1;
    }
    stage16(Bs, r_st, k_st, b0, b1, b2, b3);
    __syncthreads();
    const bf16x8 af0 = *(const bf16x8*)&As[arow0 * 32 + ((lg ^ swz(arow0)) << 3)];
    const bf16x8 af1 = *(const bf16x8*)&As[arow1 * 32 + ((lg ^ swz(arow1)) << 3)];
#pragma unroll
    for (int ct = 0; ct < 8; ++ct) {
      const int brow = ct * 16 + lm;
      const bf16x8 bb = *(const bf16x8*)&Bs[brow * 32 + ((lg ^ swz(brow)) << 3)];
      acc[0][ct] = __builtin_amdgcn_mfma_f32_16x16x32_bf16(af0, bb, acc[0][ct], 0, 0, 0);
      acc[1][ct] = __builtin_amdgcn_mfma_f32_16x16x32_bf16(af1, bb, acc[1][ct], 0, 0, 0);
    }
  }

#pragma unroll
  for (int rt = 0; rt < 2; ++rt)
#pragma unroll
    for (int r = 0; r < 4; ++r) {
      const int row = row0 + w * 32 + rt * 16 + lg * 4 + r;
#pragma unroll
      for (int ct = 0; ct < 8; ++ct)
        C[(size_t)row * kHid + col0 + ct * 16 + lm] = acc[rt][ct][r];
    }
}

}  // namespace

extern "C" void kernel_launch(void* const* d_in, const int* in_sizes, int n_in,
                              void* d_out, int out_size, void* d_ws, size_t ws_size,
                              hipStream_t stream) {
  (void)in_sizes; (void)n_in; (void)out_size; (void)ws_size;
  const float* H = (const float*)d_in[0];
  const float* cosb = (const float*)d_in[1];
  const float* sinb = (const float*)d_in[2];
  const float* Wqkv = (const float*)d_in[3];
  const float* Wo = (const float*)d_in[4];
  const int* slots = (const int*)d_in[5];
  const float* ck = (const float*)d_in[6];
  const float* cv = (const float*)d_in[7];

  float* out = (float*)d_out;
  float* ock = out + (size_t)kT * kHid;             // new_cache_k (f32)
  float* ocv = ock + (size_t)kNSlots * kNH * kHS;   // new_cache_v (f32)

  short* Qb = (short*)out;       // borrow out region (dead until out_gemm)
  short* Kb = Qb + (size_t)kT * kHid;
  short* Vb = (short*)d_ws;
  short* abuf = Vb + (size_t)kT * kHid;

  const size_t cache_bytes = (size_t)kNSlots * kNH * kHS * sizeof(float);
  hipMemcpyAsync(ock, ck, cache_bytes, hipMemcpyDeviceToDevice, stream);
  hipMemcpyAsync(ocv, cv, cache_bytes, hipMemcpyDeviceToDevice, stream);

  qkv_gemm_kernel<<<dim3(kT / 128, 24), 256, 0, stream>>>(
      H, Wqkv, cosb, sinb, slots, Qb, Kb, Vb, ock, ocv);
  attn_kernel<<<256, 512, 0, stream>>>(Qb, Kb, Vb, abuf);
  out_gemm_kernel<<<dim3(kT / 128, kHid / 128), 256, 0, stream>>>(abuf, Wo, out);
}

// Round 9
// 230.284 us; speedup vs baseline: 1.0563x; 1.0538x over previous
//
#include <hip/hip_runtime.h>
#include <hip/hip_bf16.h>

namespace {

constexpr int kT = 4096;
constexpr int kHid = 1024;
constexpr int kNH = 8;
constexpr int kHS = 128;
constexpr int kNSlots = 8192;
constexpr float kEps = 1e-6f;
constexpr float kQScale = 0.12753102242f;                 // 128^-0.5 * log2(e)
constexpr float kNeg = -1e30f;

typedef __attribute__((ext_vector_type(8))) short bf16x8;
typedef __attribute__((ext_vector_type(4))) float f32x4;
typedef __attribute__((ext_vector_type(16))) float f32x16;

__device__ __forceinline__ short f2bf(float x) {
  unsigned u = __builtin_bit_cast(unsigned, x);
  unsigned r = (u + 0x7FFFu + ((u >> 16) & 1u)) >> 16;
  return (short)r;
}

__device__ __forceinline__ bf16x8 pack_bf8(float4 a, float4 b) {
  bf16x8 r;
  r[0] = f2bf(a.x); r[1] = f2bf(a.y); r[2] = f2bf(a.z); r[3] = f2bf(a.w);
  r[4] = f2bf(b.x); r[5] = f2bf(b.y); r[6] = f2bf(b.z); r[7] = f2bf(b.w);
  return r;
}

__device__ __forceinline__ unsigned cvt_pk_bf16(float lo, float hi_) {
  unsigned r;
  asm("v_cvt_pk_bf16_f32 %0, %1, %2" : "=v"(r) : "v"(lo), "v"(hi_));
  return r;
}

__device__ __forceinline__ bf16x8 frag_from(unsigned w0, unsigned w1,
                                            unsigned w2, unsigned w3) {
  union { unsigned u[4]; bf16x8 v; } t;
  t.u[0] = w0; t.u[1] = w1; t.u[2] = w2; t.u[3] = w3;
  return t.v;
}

// Async global->LDS, 16B per lane. LDS dest = wave-uniform base + lane*16.
__device__ __forceinline__ void async16(const short* g, short* l) {
  __builtin_amdgcn_global_load_lds(
      (const __attribute__((address_space(1))) unsigned*)g,
      (__attribute__((address_space(3))) unsigned*)l, 16, 0, 0);
}

// 16B-slot XOR swizzle for [row][32 bf16] LDS tiles in the qkv A path.
__device__ __forceinline__ int swz(int r) { return ((r >> 1) ^ (r >> 3)) & 3; }

__device__ __forceinline__ void stage16(short* tile, int r, int k0,
                                        float4 a, float4 b, float4 c, float4 d) {
  const int sw = swz(r);
  const int s0 = k0 >> 3;  // 0 or 2
  *(bf16x8*)&tile[r * 32 + (((s0 + 0) ^ sw) << 3)] = pack_bf8(a, b);
  *(bf16x8*)&tile[r * 32 + (((s0 + 1) ^ sw) << 3)] = pack_bf8(c, d);
}

// Attention K tile: [64 key rows][128 d shorts] = 256B rows, 16-slot swizzle.
__device__ __forceinline__ short* kptr(short* base, int r, int c) {
  return (short*)((char*)base + ((r * 256 + c * 2) ^ ((r & 15) << 4)));
}
__device__ __forceinline__ const short* kptr(const short* base, int r, int c) {
  return (const short*)((const char*)base + ((r * 256 + c * 2) ^ ((r & 15) << 4)));
}
// Attention V tile, packed: V^T[d][k] at row=d>>1, col=(d&1)*64+k -> 256B rows.
__device__ __forceinline__ short* vptr2(short* base, int d, int k) {
  const int row = d >> 1;
  return (short*)((char*)base +
                  ((row * 256 + ((d & 1) * 64 + k) * 2) ^ ((row & 15) << 4)));
}
__device__ __forceinline__ const short* vptr2(const short* base, int d, int k) {
  const int row = d >> 1;
  return (const short*)((const char*)base +
                  ((row * 256 + ((d & 1) * 64 + k) * 2) ^ ((row & 15) << 4)));
}

// ---------------------------------------------------------------------------
// f32 -> bf16 elementwise convert (grid-exact, 8 elems/thread).
// ---------------------------------------------------------------------------
__global__ __launch_bounds__(256)
void cvt_kernel(const float* __restrict__ in, short* __restrict__ out) {
  const int i = (blockIdx.x * 256 + threadIdx.x) * 8;
  const float4 a = *(const float4*)(in + i);
  const float4 b = *(const float4*)(in + i + 4);
  *(bf16x8*)(out + i) = pack_bf8(a, b);
}

// ---------------------------------------------------------------------------
// QKV GEMM (bf16 MFMA). A (H, f32) reg-staged+converted; B (Wqkv, pre-cvt
// bf16) via global_load_lds with pre-swizzled source (2-way banks, free).
// Epilogue: l2norm + RoPE; Q pre-scaled by kScale*log2(e).
// ---------------------------------------------------------------------------
__global__ __launch_bounds__(256)
void qkv_gemm_kernel(const float* __restrict__ H, const short* __restrict__ Wq,
                     const float* __restrict__ cosb, const float* __restrict__ sinb,
                     const int* __restrict__ slots,
                     short* __restrict__ Qb, short* __restrict__ Kb,
                     short* __restrict__ Vb,
                     float* __restrict__ ock, float* __restrict__ ocv) {
  __shared__ short As[128 * 32];
  __shared__ short Bs[128 * 32];
  const int row0 = blockIdx.x * 128;
  const int bc = blockIdx.y;            // 0..7 q, 8..15 k, 16..23 v
  const int col0 = bc * 128;
  const int tid = threadIdx.x;
  const int lane = tid & 63, w = tid >> 6;
  const int lm = lane & 15, lg = lane >> 4;
  const int r_st = tid >> 1, k_st = (tid & 1) * 16;
  const int bslot = lg ^ ((lm >> 1) & 3);      // lane-constant read-slot XOR

  // B staging source (pre-swizzled chunk) + linear LDS dest (= lane*16B).
  const int srow = tid >> 2;
  const int schunk = (tid & 3) ^ ((tid >> 3) & 3);
  const short* bsrc = Wq + (size_t)(col0 + srow) * kHid + schunk * 8;
  short* bdst = &Bs[tid * 8];

  f32x4 acc[2][8];
#pragma unroll
  for (int rt = 0; rt < 2; ++rt)
#pragma unroll
    for (int ct = 0; ct < 8; ++ct) acc[rt][ct] = (f32x4){0.f, 0.f, 0.f, 0.f};

  const float* ap = H + (size_t)(row0 + r_st) * kHid + k_st;
  const int arow0 = w * 32 + lm, arow1 = w * 32 + 16 + lm;

  for (int k0 = 0; k0 < kHid; k0 += 32) {
    const float4 a0 = *(const float4*)(ap + k0);
    const float4 a1 = *(const float4*)(ap + k0 + 4);
    const float4 a2 = *(const float4*)(ap + k0 + 8);
    const float4 a3 = *(const float4*)(ap + k0 + 12);
    __syncthreads();
    async16(bsrc + k0, bdst);
    async16(bsrc + (size_t)64 * kHid + k0, bdst + 64 * 32);
    stage16(As, r_st, k_st, a0, a1, a2, a3);
    __syncthreads();
    const bf16x8 af0 = *(const bf16x8*)&As[arow0 * 32 + ((lg ^ swz(arow0)) << 3)];
    const bf16x8 af1 = *(const bf16x8*)&As[arow1 * 32 + ((lg ^ swz(arow1)) << 3)];
#pragma unroll
    for (int ct = 0; ct < 8; ++ct) {
      const bf16x8 bb = *(const bf16x8*)&Bs[(ct * 16 + lm) * 32 + bslot * 8];
      acc[0][ct] = __builtin_amdgcn_mfma_f32_16x16x32_bf16(af0, bb, acc[0][ct], 0, 0, 0);
      acc[1][ct] = __builtin_amdgcn_mfma_f32_16x16x32_bf16(af1, bb, acc[1][ct], 0, 0, 0);
    }
  }

  const bool isv = (bc >= 16);
  const int h = bc & 7;
#pragma unroll
  for (int rt = 0; rt < 2; ++rt) {
#pragma unroll
    for (int r = 0; r < 4; ++r) {
      const int t = row0 + w * 32 + rt * 16 + lg * 4 + r;
      const int slot = slots[t];
      if (!isv) {
        float ss = 0.f;
#pragma unroll
        for (int ct = 0; ct < 8; ++ct) ss = fmaf(acc[rt][ct][r], acc[rt][ct][r], ss);
        ss += __shfl_xor(ss, 1);
        ss += __shfl_xor(ss, 2);
        ss += __shfl_xor(ss, 4);
        ss += __shfl_xor(ss, 8);
        const float rs = rsqrtf(ss * (1.f / 128.f) + kEps);
#pragma unroll
        for (int ct = 0; ct < 8; ++ct) {
          const int col = ct * 16 + lm;
          const float x = acc[rt][ct][r] * rs;
          const float partner = __shfl_xor(x, 1);
          const float c = cosb[t * 64 + (col >> 1)];
          const float s = sinb[t * 64 + (col >> 1)];
          const float val = (lm & 1) ? fmaf(partner, s, x * c) : fmaf(-partner, s, x * c);
          if (bc < 8) {
            Qb[(size_t)t * kHid + h * kHS + col] = f2bf(val * kQScale);
          } else {
            ock[(size_t)slot * kHid + h * kHS + col] = val;
            Kb[(size_t)t * kHid + h * kHS + col] = f2bf(val);
          }
        }
      } else {
#pragma unroll
        for (int ct = 0; ct < 8; ++ct) {
          const int col = ct * 16 + lm;
          const float val = acc[rt][ct][r];
          ocv[(size_t)slot * kHid + h * kHS + col] = val;
          Vb[(size_t)t * kHid + h * kHS + col] = f2bf(val);
        }
      }
    }
  }
}

// ---------------------------------------------------------------------------
// Flash attention v8 = v6 skeleton + manually hoisted fragment loads:
// 16 K-frags -> regs -> QK^T; 16 V-frag reads issued before softmax (drain
// under VALU); PV from regs. launch_bounds(256,1) frees the VGPR budget.
// Grid 256, block = (head, pair a) processing q-tiles {63-a, a} sequentially.
// ---------------------------------------------------------------------------
__global__ __launch_bounds__(256, 1)
void attn_kernel(const short* __restrict__ Qb, const short* __restrict__ Kb,
                 const short* __restrict__ Vb, short* __restrict__ abuf) {
  __shared__ short Ks[2][64 * 128];   // [buf][key][d], swizzled, 256B rows
  __shared__ short Vp[2][64 * 128];   // [buf][d>>1][(d&1)*64+k], swizzled
  __shared__ float bcast[2][32];      // per-consumer-wave alpha / 1/l

  const int flat = blockIdx.x;
  const int h = flat & 7;             // XCD round-robin -> head locality
  const int a = flat >> 3;            // 0..31: pair {63-a, a}
  const int tid = threadIdx.x;
  const int w = tid >> 6;
  const int lane = tid & 63;
  const int lq = lane & 31, hi = lane >> 5;
  const bool consumer = (w < 2);
  const int wc = w & 1;

  if (!consumer) {
    // -------- producer: stage K (row-major) + V (packed-T), dbuf --------
    const int ptid = wc * 64 + lane;               // 0..127
    const int krow = ptid >> 1, kcol = (ptid & 1) * 64;
    const int vk = (ptid & 31) * 2, vd0 = (ptid >> 5) * 4;

    auto stage = [&](int j0, short* KsB, short* VpB) {
      const short* kp = Kb + (size_t)(j0 + krow) * kHid + h * kHS + kcol;
      bf16x8 kr[8];
#pragma unroll
      for (int u = 0; u < 8; ++u) kr[u] = *(const bf16x8*)(kp + u * 8);
      ushort4 va[8], vb4[8];
#pragma unroll
      for (int p = 0; p < 8; ++p) {
        const int d0 = vd0 + p * 16;
        va[p] = *(const ushort4*)&Vb[(size_t)(j0 + vk) * kHid + h * kHS + d0];
        vb4[p] = *(const ushort4*)&Vb[(size_t)(j0 + vk + 1) * kHid + h * kHS + d0];
      }
#pragma unroll
      for (int u = 0; u < 8; ++u) *(bf16x8*)kptr(KsB, krow, kcol + u * 8) = kr[u];
#pragma unroll
      for (int p = 0; p < 8; ++p) {
        const int d0 = vd0 + p * 16;
        const unsigned lo[4] = {va[p].x, va[p].y, va[p].z, va[p].w};
        const unsigned hh[4] = {vb4[p].x, vb4[p].y, vb4[p].z, vb4[p].w};
#pragma unroll
        for (int ii = 0; ii < 4; ++ii)
          *(unsigned*)vptr2(VpB, d0 + ii, vk) = lo[ii] | (hh[ii] << 16);
      }
    };

#pragma unroll 1
    for (int phase = 0; phase < 2; ++phase) {
      const int qt = phase ? a : (63 - a);
      const int nsteps = qt + 1;
      stage(0, Ks[0], Vp[0]);
      __syncthreads();
#pragma unroll 1
      for (int s = 0; s < nsteps; ++s) {
        if (s + 1 < nsteps) stage((s + 1) * 64, Ks[(s + 1) & 1], Vp[(s + 1) & 1]);
        __syncthreads();
      }
    }
    return;
  }

  // -------------------------- consumer ---------------------------------
#pragma unroll 1
  for (int phase = 0; phase < 2; ++phase) {
    const int qt = phase ? a : (63 - a);
    const int q0 = qt * 64;
    const int nsteps = qt + 1;
    const int qrow = q0 + wc * 32 + lq;            // this lane's q row

    bf16x8 qf[8];
    {
      const short* qp = Qb + (size_t)qrow * kHid + h * kHS + hi * 8;
#pragma unroll
      for (int dc = 0; dc < 8; ++dc) qf[dc] = *(const bf16x8*)(qp + dc * 16);
    }

    float m = kNeg, l = 0.f;
    f32x16 O[4];
#pragma unroll
    for (int dt = 0; dt < 4; ++dt)
#pragma unroll
      for (int r = 0; r < 16; ++r) O[dt][r] = 0.f;

    __syncthreads();  // buf0 staged

#pragma unroll 1
    for (int s = 0; s < nsteps; ++s) {
      const int j0 = s * 64;
      const short* KsB = Ks[s & 1];
      const short* VpB = Vp[s & 1];

      // ---- hoisted K-fragment loads (batched ds_read, one drain).
      bf16x8 kf[16];
#pragma unroll
      for (int dc = 0; dc < 8; ++dc)
#pragma unroll
        for (int kb = 0; kb < 2; ++kb)
          kf[dc * 2 + kb] = *(const bf16x8*)kptr(KsB, kb * 32 + lq, dc * 16 + hi * 8);

      // ---- S^T = K · Q (exp2-domain scores).
      f32x16 st[2];
#pragma unroll
      for (int kb = 0; kb < 2; ++kb)
#pragma unroll
        for (int r = 0; r < 16; ++r) st[kb][r] = 0.f;

      __builtin_amdgcn_s_setprio(1);
#pragma unroll
      for (int dc = 0; dc < 8; ++dc) {
        st[0] = __builtin_amdgcn_mfma_f32_32x32x16_bf16(kf[dc * 2 + 0], qf[dc], st[0], 0, 0, 0);
        st[1] = __builtin_amdgcn_mfma_f32_32x32x16_bf16(kf[dc * 2 + 1], qf[dc], st[1], 0, 0, 0);
      }
      __builtin_amdgcn_s_setprio(0);

      // ---- V-fragment loads issued now; they drain under the softmax VALU.
      bf16x8 vf[16];
#pragma unroll
      for (int kc = 0; kc < 4; ++kc)
#pragma unroll
        for (int dt = 0; dt < 4; ++dt)
          vf[kc * 4 + dt] = *(const bf16x8*)vptr2(VpB, dt * 32 + lq, kc * 16 + hi * 8);

      // ---- causal mask (diagonal tile only).
      if (j0 == q0) {
#pragma unroll
        for (int kb = 0; kb < 2; ++kb)
#pragma unroll
          for (int r = 0; r < 16; ++r) {
            const int ka = j0 + kb * 32 + (r & 3) + 8 * (r >> 2) + 4 * hi;
            if (ka > qrow) st[kb][r] = kNeg;
          }
      }

      // ---- online softmax with defer-max (T13).
      float tt[16];
#pragma unroll
      for (int r = 0; r < 16; ++r) tt[r] = fmaxf(st[0][r], st[1][r]);
#pragma unroll
      for (int d = 8; d >= 1; d >>= 1)
#pragma unroll
        for (int r = 0; r < d; ++r) tt[r] = fmaxf(tt[r], tt[r + d]);
      const float pmax = fmaxf(tt[0], __shfl_xor(tt[0], 32));

      if (!__all(pmax - m <= 8.f)) {
        const float mnew = fmaxf(m, pmax);
        const float alpha = exp2f(m - mnew);
        m = mnew;
        l *= alpha;
        if (!hi) bcast[wc][lq] = alpha;
        float4 av[4];
#pragma unroll
        for (int g4 = 0; g4 < 4; ++g4)
          av[g4] = *(const float4*)&bcast[wc][8 * g4 + 4 * hi];
#pragma unroll
        for (int dt = 0; dt < 4; ++dt)
#pragma unroll
          for (int r = 0; r < 16; ++r) O[dt][r] *= av[r >> 2][r & 3];
      }

      float ts[16];
#pragma unroll
      for (int kb = 0; kb < 2; ++kb)
#pragma unroll
        for (int r = 0; r < 16; ++r) st[kb][r] = exp2f(st[kb][r] - m);
#pragma unroll
      for (int r = 0; r < 16; ++r) ts[r] = st[0][r] + st[1][r];
#pragma unroll
      for (int d = 8; d >= 1; d >>= 1)
#pragma unroll
        for (int r = 0; r < d; ++r) ts[r] += ts[r + d];
      l += ts[0] + __shfl_xor(ts[0], 32);

      // ---- P -> bf16 A-fragments via cvt_pk + lane^32 exchange (T12).
      bf16x8 pf[4];
#pragma unroll
      for (int kb = 0; kb < 2; ++kb) {
        unsigned wq[8];
#pragma unroll
        for (int u = 0; u < 8; ++u)
          wq[u] = cvt_pk_bf16(st[kb][2 * u], st[kb][2 * u + 1]);
        {
          const unsigned z0 = hi ? wq[0] : wq[2];
          const unsigned z1 = hi ? wq[1] : wq[3];
          const unsigned s0 = __shfl_xor(z0, 32);
          const unsigned s1 = __shfl_xor(z1, 32);
          pf[2 * kb] = frag_from(hi ? s0 : wq[0], hi ? s1 : wq[1],
                                 hi ? wq[2] : s0, hi ? wq[3] : s1);
        }
        {
          const unsigned z0 = hi ? wq[4] : wq[6];
          const unsigned z1 = hi ? wq[5] : wq[7];
          const unsigned s0 = __shfl_xor(z0, 32);
          const unsigned s1 = __shfl_xor(z1, 32);
          pf[2 * kb + 1] = frag_from(hi ? s0 : wq[4], hi ? s1 : wq[5],
                                     hi ? wq[6] : s0, hi ? wq[7] : s1);
        }
      }

      // ---- O += P · V (all operands in registers).
      __builtin_amdgcn_s_setprio(1);
#pragma unroll
      for (int kc = 0; kc < 4; ++kc) {
#pragma unroll
        for (int dt = 0; dt < 4; ++dt)
          O[dt] = __builtin_amdgcn_mfma_f32_32x32x16_bf16(pf[kc], vf[kc * 4 + dt], O[dt], 0, 0, 0);
      }
      __builtin_amdgcn_s_setprio(0);

      __syncthreads();  // next buf staged; this buf free
    }

    // ---- write out: O col = d = dt*32+lq, row = (r&3)+8*(r>>2)+4*hi.
    if (!hi) bcast[wc][lq] = 1.f / l;
    float4 iv[4];
#pragma unroll
    for (int g4 = 0; g4 < 4; ++g4) iv[g4] = *(const float4*)&bcast[wc][8 * g4 + 4 * hi];
#pragma unroll
    for (int dt = 0; dt < 4; ++dt)
#pragma unroll
      for (int r = 0; r < 16; ++r) {
        const int mrow = (r & 3) + 8 * (r >> 2) + 4 * hi;
        const int t = q0 + wc * 32 + mrow;
        abuf[(size_t)t * kHid + h * kHS + dt * 32 + lq] =
            f2bf(O[dt][r] * iv[r >> 2][r & 3]);
      }
  }
}

// ---------------------------------------------------------------------------
// Output GEMM: A (abuf bf16) and B (Wo pre-cvt bf16) both via global_load_lds
// with pre-swizzled sources (2-way banks, free).
// ---------------------------------------------------------------------------
__global__ __launch_bounds__(256)
void out_gemm_kernel(const short* __restrict__ A, const short* __restrict__ W,
                     float* __restrict__ C) {
  __shared__ short As[128 * 32];
  __shared__ short Bs[128 * 32];
  const int row0 = blockIdx.x * 128;
  const int col0 = blockIdx.y * 128;
  const int tid = threadIdx.x;
  const int lane = tid & 63, w = tid >> 6;
  const int lm = lane & 15, lg = lane >> 4;
  const int bslot = lg ^ ((lm >> 1) & 3);

  const int srow = tid >> 2;
  const int schunk = (tid & 3) ^ ((tid >> 3) & 3);
  const short* asrc = A + (size_t)(row0 + srow) * kHid + schunk * 8;
  const short* bsrc = W + (size_t)(col0 + srow) * kHid + schunk * 8;
  short* adst = &As[tid * 8];
  short* bdst = &Bs[tid * 8];

  f32x4 acc[2][8];
#pragma unroll
  for (int rt = 0; rt < 2; ++rt)
#pragma unroll
    for (int ct = 0; ct < 8; ++ct) acc[rt][ct] = (f32x4){0.f, 0.f, 0.f, 0.f};

  const int arow0 = w * 32 + lm, arow1 = w * 32 + 16 + lm;

  for (int k0 = 0; k0 < kHid; k0 += 32) {
    __syncthreads();
    async16(asrc + k0, adst);
    async16(asrc + (size_t)64 * kHid + k0, adst + 64 * 32);
    async16(bsrc + k0, bdst);
    async16(bsrc + (size_t)64 * kHid + k0, bdst + 64 * 32);
    __syncthreads();
    const bf16x8 af0 = *(const bf16x8*)&As[arow0 * 32 + bslot * 8];
    const bf16x8 af1 = *(const bf16x8*)&As[arow1 * 32 + bslot * 8];
#pragma unroll
    for (int ct = 0; ct < 8; ++ct) {
      const bf16x8 bb = *(const bf16x8*)&Bs[(ct * 16 + lm) * 32 + bslot * 8];
      acc[0][ct] = __builtin_amdgcn_mfma_f32_16x16x32_bf16(af0, bb, acc[0][ct], 0, 0, 0);
      acc[1][ct] = __builtin_amdgcn_mfma_f32_16x16x32_bf16(af1, bb, acc[1][ct], 0, 0, 0);
    }
  }

#pragma unroll
  for (int rt = 0; rt < 2; ++rt)
#pragma unroll
    for (int r = 0; r < 4; ++r) {
      const int row = row0 + w * 32 + rt * 16 + lg * 4 + r;
#pragma unroll
      for (int ct = 0; ct < 8; ++ct)
        C[(size_t)row * kHid + col0 + ct * 16 + lm] = acc[rt][ct][r];
    }
}

}  // namespace

extern "C" void kernel_launch(void* const* d_in, const int* in_sizes, int n_in,
                              void* d_out, int out_size, void* d_ws, size_t ws_size,
                              hipStream_t stream) {
  (void)in_sizes; (void)n_in; (void)out_size; (void)ws_size;
  const float* H = (const float*)d_in[0];
  const float* cosb = (const float*)d_in[1];
  const float* sinb = (const float*)d_in[2];
  const float* Wqkv = (const float*)d_in[3];
  const float* Wo = (const float*)d_in[4];
  const int* slots = (const int*)d_in[5];
  const float* ck = (const float*)d_in[6];
  const float* cv = (const float*)d_in[7];

  float* out = (float*)d_out;
  float* ock = out + (size_t)kT * kHid;             // new_cache_k (f32)
  float* ocv = ock + (size_t)kNSlots * kNH * kHS;   // new_cache_v (f32)

  short* Qb = (short*)out;          // borrow out region (dead until out_gemm)
  short* Kb = Qb + (size_t)kT * kHid;
  short* Vb = (short*)d_ws;
  short* abuf = Vb + (size_t)kT * kHid;
  short* Wqb = abuf;                // time-shares abuf (dead before attn)
  short* Wob = Vb;                  // time-shares Vb (converted after attn)

  const size_t cache_bytes = (size_t)kNSlots * kNH * kHS * sizeof(float);
  hipMemcpyAsync(ock, ck, cache_bytes, hipMemcpyDeviceToDevice, stream);
  hipMemcpyAsync(ocv, cv, cache_bytes, hipMemcpyDeviceToDevice, stream);

  // Wqkv: 3*kHid*kHid elems / (8 per thread * 256 threads) = 1536 blocks.
  cvt_kernel<<<(3 * kHid * kHid) / (8 * 256), 256, 0, stream>>>(Wqkv, Wqb);
  qkv_gemm_kernel<<<dim3(kT / 128, 24), 256, 0, stream>>>(
      H, Wqb, cosb, sinb, slots, Qb, Kb, Vb, ock, ocv);
  attn_kernel<<<256, 256, 0, stream>>>(Qb, Kb, Vb, abuf);
  // Wo: kHid*kHid / 2048 = 512 blocks.
  cvt_kernel<<<(kHid * kHid) / (8 * 256), 256, 0, stream>>>(Wo, Wob);
  out_gemm_kernel<<<dim3(kT / 128, kHid / 128), 256, 0, stream>>>(abuf, Wob, out);
}